// Round 1
// baseline (168.660 us; speedup 1.0000x reference)
//
#include <hip/hip_runtime.h>
#include <hip/hip_bf16.h>

// Problem constants
#define B_    64
#define C_    64
#define N_    22
#define T_    1024
#define O_    64
#define KTOT  1408      // C_*N_
#define KSTEPS 44       // KTOT/32

typedef __bf16 bf16x8 __attribute__((ext_vector_type(8)));
typedef float  f32x4  __attribute__((ext_vector_type(4)));

// ---------------------------------------------------------------------------
// prep1: compute C1 = s, C2 = 2 s^2 - I  (22x22 each) and const[o]
// ---------------------------------------------------------------------------
__global__ void prep1(const float* __restrict__ adjp,
                      const float* __restrict__ aggw,
                      const float* __restrict__ chebb,
                      const float* __restrict__ aggb,
                      float* __restrict__ Cbuf,    // [2][484]
                      float* __restrict__ constv)  // [64]
{
    __shared__ float adj[484];
    __shared__ float s[484];
    __shared__ float dis[22];
    int tid = threadIdx.x;

    if (tid < 484) {
        int i = tid / 22, j = tid % 22;
        float a = 0.5f * (1.f / (1.f + expf(-adjp[i * 22 + j])) +
                          1.f / (1.f + expf(-adjp[j * 22 + i])));
        if (i == j) a = 0.f;
        adj[tid] = a;
    }
    __syncthreads();
    if (tid < 22) {
        float d = 0.f;
        for (int n = 0; n < 22; ++n) d += adj[tid * 22 + n];
        dis[tid] = rsqrtf(d);
    }
    __syncthreads();
    if (tid < 484) {
        int i = tid / 22, j = tid % 22;
        float sv = -dis[i] * adj[tid] * dis[j];
        s[tid] = sv;
        Cbuf[tid] = sv;                 // C1
    }
    __syncthreads();
    if (tid < 484) {
        int i = tid / 22, j = tid % 22;
        float acc = 0.f;
        for (int n = 0; n < 22; ++n) acc += s[i * 22 + n] * s[n * 22 + j];
        Cbuf[484 + tid] = 2.f * acc - (i == j ? 1.f : 0.f);   // C2
    }
    if (tid < 64) {
        // const[o] = agg_bias[o] + sum_{c',n} aggw[o,c',n] * cheb_bias[c']
        float cc = aggb[tid];
        const float* wsl = aggw + tid * (C_ * N_);
        for (int e = 0; e < C_ * N_; ++e) cc += wsl[e] * chebb[e / N_];
        constv[tid] = cc;
    }
}

// ---------------------------------------------------------------------------
// prep2: F[qi][o][c'][v] = sum_n aggw[o,c',n] * C_{qi+1}[n,v]   qi in {0,1}
// ---------------------------------------------------------------------------
__global__ void prep2(const float* __restrict__ aggw,
                      const float* __restrict__ Cbuf,
                      float* __restrict__ F)        // [2][64][1408]
{
    int qi = blockIdx.x >> 6;
    int o  = blockIdx.x & 63;
    __shared__ float Cs[484];
    __shared__ float Ws[C_ * N_];
    for (int e = threadIdx.x; e < 484; e += 256) Cs[e] = Cbuf[qi * 484 + e];
    for (int e = threadIdx.x; e < C_ * N_; e += 256) Ws[e] = aggw[o * (C_ * N_) + e];
    __syncthreads();
    for (int e = threadIdx.x; e < C_ * N_; e += 256) {
        int cp = e / N_, v = e % N_;
        float acc = 0.f;
#pragma unroll
        for (int n = 0; n < N_; ++n) acc += Ws[cp * N_ + n] * Cs[n * N_ + v];
        F[(qi * 64 + o) * (C_ * N_) + e] = acc;
    }
}

// ---------------------------------------------------------------------------
// prep3: fold into M[o,k], k=c*22+v, stored bf16 in A-fragment-major layout:
//   Mfrag[((ks*4+fo)*64 + lane)*8 + j] = M[o = fo*16 + (lane&15),
//                                          k = ks*32 + (lane>>4)*8 + j]
// ---------------------------------------------------------------------------
__global__ void prep3(const float* __restrict__ chebw,  // [3][64][64]
                      const float* __restrict__ aggw,   // [64][64][22]
                      const float* __restrict__ F,      // [2][64][1408]
                      __bf16* __restrict__ Mfrag)       // [176*512]
{
    int f  = blockIdx.x;       // 0..175
    int ks = f >> 2, fo = f & 3;
    for (int e = threadIdx.x; e < 512; e += 256) {
        int l = e >> 3, j = e & 7;
        int o = fo * 16 + (l & 15);
        int k = ks * 32 + ((l >> 4) << 3) + j;
        int c = k / N_, v = k - c * N_;
        const float* w0 = chebw + c * 64;
        const float* w1 = w0 + 4096;
        const float* w2 = w0 + 8192;
        const float* g0 = aggw + o * (C_ * N_) + v;          // q=0: C0=I -> aggw
        const float* g1 = F + o * (C_ * N_) + v;             // q=1
        const float* g2 = F + (64 + o) * (C_ * N_) + v;      // q=2
        float a0 = 0.f, a1 = 0.f, a2 = 0.f;
        for (int cp = 0; cp < 64; ++cp) {
            a0 += w0[cp] * g0[cp * N_];
            a1 += w1[cp] * g1[cp * N_];
            a2 += w2[cp] * g2[cp * N_];
        }
        Mfrag[f * 512 + e] = (__bf16)(a0 + a1 + a2);
    }
}

// ---------------------------------------------------------------------------
// main GEMM: per block (b, t-tile of 64): Y_b[64, t0:t0+64] = M @ X_b
// 4 waves, wave w owns t-sub of 16 (all 64 output channels).
// No LDS: A-frags from fragment-major M (L2-resident), B-frags gathered
// from x directly in fragment order with fp32->bf16 in-register convert.
// ---------------------------------------------------------------------------
__global__ __launch_bounds__(256) void gemm_main(
    const float* __restrict__ x,
    const __bf16* __restrict__ Mfrag,
    const float* __restrict__ constv,
    float* __restrict__ y)
{
    int bid  = blockIdx.x;
    int b    = bid >> 4;
    int tt   = bid & 15;
    int wave = threadIdx.x >> 6;
    int lane = threadIdx.x & 63;
    int tcol = lane & 15;
    int kg   = lane >> 4;
    int t0   = tt * 64 + wave * 16;

    const float* xp = x + (size_t)b * (KTOT * T_) + (size_t)(kg * 8) * T_ + (t0 + tcol);

    f32x4 acc[4];
#pragma unroll
    for (int fo = 0; fo < 4; ++fo) acc[fo] = (f32x4){0.f, 0.f, 0.f, 0.f};

    // prologue: load ks=0
    float  xc[8];
    bf16x8 ac[4];
#pragma unroll
    for (int j = 0; j < 8; ++j) xc[j] = xp[(size_t)j * T_];
#pragma unroll
    for (int fo = 0; fo < 4; ++fo)
        ac[fo] = *reinterpret_cast<const bf16x8*>(Mfrag + ((size_t)(fo * 64 + lane)) * 8);

    for (int ks = 0; ks < KSTEPS - 1; ++ks) {
        // prefetch ks+1
        float  xn[8];
        bf16x8 an[4];
        const float* xq = xp + (size_t)(ks + 1) * 32 * T_;
#pragma unroll
        for (int j = 0; j < 8; ++j) xn[j] = xq[(size_t)j * T_];
#pragma unroll
        for (int fo = 0; fo < 4; ++fo)
            an[fo] = *reinterpret_cast<const bf16x8*>(
                Mfrag + ((size_t)(((ks + 1) * 4 + fo) * 64 + lane)) * 8);

        // compute ks
        bf16x8 bx;
#pragma unroll
        for (int j = 0; j < 8; ++j) bx[j] = (__bf16)xc[j];
#pragma unroll
        for (int fo = 0; fo < 4; ++fo)
            acc[fo] = __builtin_amdgcn_mfma_f32_16x16x32_bf16(ac[fo], bx, acc[fo], 0, 0, 0);

#pragma unroll
        for (int j = 0; j < 8; ++j) xc[j] = xn[j];
#pragma unroll
        for (int fo = 0; fo < 4; ++fo) ac[fo] = an[fo];
    }
    // epilogue: ks = KSTEPS-1
    {
        bf16x8 bx;
#pragma unroll
        for (int j = 0; j < 8; ++j) bx[j] = (__bf16)xc[j];
#pragma unroll
        for (int fo = 0; fo < 4; ++fo)
            acc[fo] = __builtin_amdgcn_mfma_f32_16x16x32_bf16(ac[fo], bx, acc[fo], 0, 0, 0);
    }

    // store: D row = o = fo*16 + (lane>>4)*4 + r, col = t = t0 + (lane&15)
    float* yp = y + (size_t)b * (O_ * T_) + (t0 + tcol);
#pragma unroll
    for (int fo = 0; fo < 4; ++fo) {
#pragma unroll
        for (int r = 0; r < 4; ++r) {
            int o = fo * 16 + kg * 4 + r;
            yp[(size_t)o * T_] = acc[fo][r] + constv[o];
        }
    }
}

// ---------------------------------------------------------------------------
extern "C" void kernel_launch(void* const* d_in, const int* in_sizes, int n_in,
                              void* d_out, int out_size, void* d_ws, size_t ws_size,
                              hipStream_t stream)
{
    (void)in_sizes; (void)n_in; (void)out_size; (void)ws_size;
    const float* x     = (const float*)d_in[0];
    const float* adjp  = (const float*)d_in[1];
    const float* chebw = (const float*)d_in[2];
    const float* chebb = (const float*)d_in[3];
    const float* aggw  = (const float*)d_in[4];
    const float* aggb  = (const float*)d_in[5];
    float* y = (float*)d_out;

    char* ws = (char*)d_ws;
    float*  Cbuf   = (float*)(ws);                    //   968 floats
    float*  constv = (float*)(ws + 4096);             //    64 floats
    float*  F      = (float*)(ws + 8192);             // 180224 floats (720896 B)
    __bf16* Mfrag  = (__bf16*)(ws + 8192 + 720896);   //  90112 bf16  (180224 B)

    hipLaunchKernelGGL(prep1, dim3(1),    dim3(512), 0, stream, adjp, aggw, chebb, aggb, Cbuf, constv);
    hipLaunchKernelGGL(prep2, dim3(128),  dim3(256), 0, stream, aggw, Cbuf, F);
    hipLaunchKernelGGL(prep3, dim3(176),  dim3(256), 0, stream, chebw, aggw, F, Mfrag);
    hipLaunchKernelGGL(gemm_main, dim3(1024), dim3(256), 0, stream, x, Mfrag, constv, y);
}

// Round 2
// 148.051 us; speedup vs baseline: 1.1392x; 1.1392x over previous
//
#include <hip/hip_runtime.h>
#include <hip/hip_bf16.h>

// Problem constants
#define B_    64
#define C_    64
#define N_    22
#define T_    1024
#define O_    64
#define KTOT  1408      // C_*N_
#define KSTEPS 44       // KTOT/32

typedef __bf16 bf16x8 __attribute__((ext_vector_type(8)));
typedef float  f32x4  __attribute__((ext_vector_type(4)));

typedef __attribute__((address_space(1))) float f32_g;
typedef __attribute__((address_space(3))) float f32_l;

// ---------------------------------------------------------------------------
// prep1: compute C1 = s, C2 = 2 s^2 - I  (22x22 each) and const[o]
// ---------------------------------------------------------------------------
__global__ void prep1(const float* __restrict__ adjp,
                      const float* __restrict__ aggw,
                      const float* __restrict__ chebb,
                      const float* __restrict__ aggb,
                      float* __restrict__ Cbuf,    // [2][484]
                      float* __restrict__ constv)  // [64]
{
    __shared__ float adj[484];
    __shared__ float s[484];
    __shared__ float dis[22];
    int tid = threadIdx.x;

    if (tid < 484) {
        int i = tid / 22, j = tid % 22;
        float a = 0.5f * (1.f / (1.f + expf(-adjp[i * 22 + j])) +
                          1.f / (1.f + expf(-adjp[j * 22 + i])));
        if (i == j) a = 0.f;
        adj[tid] = a;
    }
    __syncthreads();
    if (tid < 22) {
        float d = 0.f;
        for (int n = 0; n < 22; ++n) d += adj[tid * 22 + n];
        dis[tid] = rsqrtf(d);
    }
    __syncthreads();
    if (tid < 484) {
        int i = tid / 22, j = tid % 22;
        float sv = -dis[i] * adj[tid] * dis[j];
        s[tid] = sv;
        Cbuf[tid] = sv;                 // C1
    }
    __syncthreads();
    if (tid < 484) {
        int i = tid / 22, j = tid % 22;
        float acc = 0.f;
        for (int n = 0; n < 22; ++n) acc += s[i * 22 + n] * s[n * 22 + j];
        Cbuf[484 + tid] = 2.f * acc - (i == j ? 1.f : 0.f);   // C2
    }
    if (tid < 64) {
        float cc = aggb[tid];
        const float* wsl = aggw + tid * (C_ * N_);
        for (int e = 0; e < C_ * N_; ++e) cc += wsl[e] * chebb[e / N_];
        constv[tid] = cc;
    }
}

// ---------------------------------------------------------------------------
// prep2: F[qi][o][c'][v] = sum_n aggw[o,c',n] * C_{qi+1}[n,v]   qi in {0,1}
// ---------------------------------------------------------------------------
__global__ void prep2(const float* __restrict__ aggw,
                      const float* __restrict__ Cbuf,
                      float* __restrict__ F)        // [2][64][1408]
{
    int qi = blockIdx.x >> 6;
    int o  = blockIdx.x & 63;
    __shared__ float Cs[484];
    __shared__ float Ws[C_ * N_];
    for (int e = threadIdx.x; e < 484; e += 256) Cs[e] = Cbuf[qi * 484 + e];
    for (int e = threadIdx.x; e < C_ * N_; e += 256) Ws[e] = aggw[o * (C_ * N_) + e];
    __syncthreads();
    for (int e = threadIdx.x; e < C_ * N_; e += 256) {
        int cp = e / N_, v = e % N_;
        float acc = 0.f;
#pragma unroll
        for (int n = 0; n < N_; ++n) acc += Ws[cp * N_ + n] * Cs[n * N_ + v];
        F[(qi * 64 + o) * (C_ * N_) + e] = acc;
    }
}

// ---------------------------------------------------------------------------
// prep3: fold into M[o,k], k=c*22+v, stored bf16 in A-fragment-major layout:
//   Mfrag[((ks*4+fo)*64 + lane)*8 + j] = M[o = fo*16 + (lane&15),
//                                          k = ks*32 + (lane>>4)*8 + j]
// ---------------------------------------------------------------------------
__global__ void prep3(const float* __restrict__ chebw,  // [3][64][64]
                      const float* __restrict__ aggw,   // [64][64][22]
                      const float* __restrict__ F,      // [2][64][1408]
                      __bf16* __restrict__ Mfrag)       // [176*512]
{
    int f  = blockIdx.x;       // 0..175
    int ks = f >> 2, fo = f & 3;
    for (int e = threadIdx.x; e < 512; e += 256) {
        int l = e >> 3, j = e & 7;
        int o = fo * 16 + (l & 15);
        int k = ks * 32 + ((l >> 4) << 3) + j;
        int c = k / N_, v = k - c * N_;
        const float* w0 = chebw + c * 64;
        const float* w1 = w0 + 4096;
        const float* w2 = w0 + 8192;
        const float* g0 = aggw + o * (C_ * N_) + v;          // q=0: C0=I -> aggw
        const float* g1 = F + o * (C_ * N_) + v;             // q=1
        const float* g2 = F + (64 + o) * (C_ * N_) + v;      // q=2
        float a0 = 0.f, a1 = 0.f, a2 = 0.f;
        for (int cp = 0; cp < 64; ++cp) {
            a0 += w0[cp] * g0[cp * N_];
            a1 += w1[cp] * g1[cp * N_];
            a2 += w2[cp] * g2[cp * N_];
        }
        Mfrag[f * 512 + e] = (__bf16)(a0 + a1 + a2);
    }
}

// ---------------------------------------------------------------------------
// main GEMM: per block (b, t-tile of 64): Y_b[64, t0:t0+64] = M @ X_b
// x staged to LDS via global_load_lds dwordx4, 3 buffers, 2-ahead prefetch,
// counted vmcnt (never 0 in steady state). XOR-swizzled t-chunks so fragment
// ds_read_b32 is conflict-free (2 lanes/bank).
// ---------------------------------------------------------------------------
__global__ __launch_bounds__(256) void gemm_main(
    const float* __restrict__ x,
    const __bf16* __restrict__ Mfrag,
    const float* __restrict__ constv,
    float* __restrict__ y)
{
    __shared__ float lds[3 * 2048];   // 3 x [32 k][64 t] fp32 = 24 KB

    const int bid  = blockIdx.x;
    const int b    = bid >> 4;
    const int tt   = bid & 15;
    const int wave = threadIdx.x >> 6;
    const int lane = threadIdx.x & 63;
    const int tcol = lane & 15;
    const int kg   = lane >> 4;

    // ---- staging: wave w covers rows w*4..w*4+3 and 16+w*4..16+w*4+3 ----
    // LDS dest is linear (gload_lds requirement); swizzle applied on SOURCE:
    // LDS[k][chunk c] holds global t-chunk  g = c ^ (((k>>3)&3)<<1)
    const int rA = wave * 4 + kg;
    const int rB = rA + 16;
    const int gA = tcol ^ (((rA >> 3) & 3) << 1);
    const int gB = tcol ^ (((rB >> 3) & 3) << 1);
    const float* srcA = x + (size_t)b * (KTOT * T_) + (size_t)rA * T_ + tt * 64 + gA * 4;
    const float* srcB = x + (size_t)b * (KTOT * T_) + (size_t)rB * T_ + tt * 64 + gB * 4;
    const int dstA = (wave * 4) * 64;        // float offset, wave-uniform
    const int dstB = (16 + wave * 4) * 64;

    // ---- fragment read addressing (inverse swizzle) ----
    // lane needs x[k = kg*8+j][t = wave*16+tcol]; global chunk g0 = wave*4+(tcol>>2)
    const int c_rd   = (wave * 4 + (tcol >> 2)) ^ (kg << 1);
    const int rd_off = kg * 512 + c_rd * 4 + (tcol & 3);   // + j*64 per j

    const __bf16* mf = Mfrag + (size_t)lane * 8;

    f32x4 acc[4];
#pragma unroll
    for (int fo = 0; fo < 4; ++fo) acc[fo] = (f32x4){0.f, 0.f, 0.f, 0.f};

    auto STAGE = [&](int ks, float* buf) {
        const float* s1 = srcA + (size_t)ks * (32 * T_);
        const float* s2 = srcB + (size_t)ks * (32 * T_);
        __builtin_amdgcn_global_load_lds((const f32_g*)s1, (f32_l*)(buf + dstA), 16, 0, 0);
        __builtin_amdgcn_global_load_lds((const f32_g*)s2, (f32_l*)(buf + dstB), 16, 0, 0);
    };
    auto PREFA = [&](bf16x8* dst, int ks) {
        const __bf16* p = mf + (size_t)ks * 2048;
#pragma unroll
        for (int fo = 0; fo < 4; ++fo)
            dst[fo] = *reinterpret_cast<const bf16x8*>(p + fo * 512);
    };
    auto COMPUTE = [&](const bf16x8* a, const float* buf) {
        float v[8];
#pragma unroll
        for (int j = 0; j < 8; ++j) v[j] = buf[rd_off + j * 64];
        bf16x8 bx;
#pragma unroll
        for (int j = 0; j < 8; ++j) bx[j] = (__bf16)v[j];
#pragma unroll
        for (int fo = 0; fo < 4; ++fo)
            acc[fo] = __builtin_amdgcn_mfma_f32_16x16x32_bf16(a[fo], bx, acc[fo], 0, 0, 0);
    };

    // ---- prologue: A(0), tiles 0 and 1 ----
    bf16x8 ac[4], an[4];
    PREFA(ac, 0);
    float* bA = lds;
    float* bB = lds + 2048;
    float* bC = lds + 4096;
    STAGE(0, bA);
    STAGE(1, bB);
    asm volatile("s_waitcnt vmcnt(2)" ::: "memory");   // tile 0 complete
    __builtin_amdgcn_s_barrier();

    // ---- main loop: 21 trips, tiles 0..41 ----
    for (int i = 0; i < 42; i += 2) {
        PREFA(an, i + 1);
        STAGE(i + 2, bC);
        COMPUTE(ac, bA);
        asm volatile("s_waitcnt vmcnt(6)" ::: "memory");   // S(i+1) done; A(i+1)+S(i+2) fly
        __builtin_amdgcn_s_barrier();

        PREFA(ac, i + 2);
        STAGE(i + 3, bA);
        COMPUTE(an, bB);
        asm volatile("s_waitcnt vmcnt(6)" ::: "memory");   // S(i+2) done; A(i+2)+S(i+3) fly
        __builtin_amdgcn_s_barrier();

        float* t = bA; bA = bC; bC = bB; bB = t;   // (bA,bB,bC) <- (bC,bA,bB)
    }

    // ---- tail: tiles 42, 43 (bA=tile42, bB=tile43) ----
    PREFA(an, 43);
    COMPUTE(ac, bA);
    asm volatile("s_waitcnt vmcnt(4)" ::: "memory");       // S(43) done
    __builtin_amdgcn_s_barrier();
    COMPUTE(an, bB);

    // ---- store ----
    float* yp = y + (size_t)b * (O_ * T_) + tt * 64 + wave * 16 + tcol;
#pragma unroll
    for (int fo = 0; fo < 4; ++fo) {
#pragma unroll
        for (int r = 0; r < 4; ++r) {
            int o = fo * 16 + kg * 4 + r;
            yp[(size_t)o * T_] = acc[fo][r] + constv[o];
        }
    }
}

// ---------------------------------------------------------------------------
extern "C" void kernel_launch(void* const* d_in, const int* in_sizes, int n_in,
                              void* d_out, int out_size, void* d_ws, size_t ws_size,
                              hipStream_t stream)
{
    (void)in_sizes; (void)n_in; (void)out_size; (void)ws_size;
    const float* x     = (const float*)d_in[0];
    const float* adjp  = (const float*)d_in[1];
    const float* chebw = (const float*)d_in[2];
    const float* chebb = (const float*)d_in[3];
    const float* aggw  = (const float*)d_in[4];
    const float* aggb  = (const float*)d_in[5];
    float* y = (float*)d_out;

    char* ws = (char*)d_ws;
    float*  Cbuf   = (float*)(ws);                    //   968 floats
    float*  constv = (float*)(ws + 4096);             //    64 floats
    float*  F      = (float*)(ws + 8192);             // 180224 floats (720896 B)
    __bf16* Mfrag  = (__bf16*)(ws + 8192 + 720896);   //  90112 bf16  (180224 B)

    hipLaunchKernelGGL(prep1, dim3(1),    dim3(512), 0, stream, adjp, aggw, chebb, aggb, Cbuf, constv);
    hipLaunchKernelGGL(prep2, dim3(128),  dim3(256), 0, stream, aggw, Cbuf, F);
    hipLaunchKernelGGL(prep3, dim3(176),  dim3(256), 0, stream, chebw, aggw, F, Mfrag);
    hipLaunchKernelGGL(gemm_main, dim3(1024), dim3(256), 0, stream, x, Mfrag, constv, y);
}